// Round 14
// baseline (272199.243 us; speedup 1.0000x reference)
//
#include <hip/hip_runtime.h>

// B=64, T=256, H=1024, L=6. Cell: h = tanh((prev + h_old) @ W^T + b1 + b2).
// v14 = v8 (PASSING 18.2ms: 8 groups x 8 batches x 32 j-blocks, W in 128
// VGPRs, data-as-flag tags, agent-scope atomics via MALL) + latency surgery:
//  1. H PREFETCH: H of cell n+1 is gathered during cell n's FMA into an LDS
//     ring (same-thread slots, cell-parity dbuf -> no barriers). v8 paid the
//     MALL round trip twice per cell (P and H); now only P stalls.
//  2. t=0 cells read h0 by PLAIN loads (no init publish, no polling).
//  3. Poll fix-loops skip s_sleep in the first iterations.
// r13 lesson: v12/v13's 88ms + 103GB FETCH was wreg=256-VGPR scratch spill
// (VGPR_Count=256, VALUBusy 5.7%); r12's "MALL BW wall" theory was wrong --
// v8 is LATENCY-bound. This keeps wreg at 128 VGPRs (peak ~200, no spill).
// Tags: y stored as y+o(t), o(t)=8+8*((t>>1)&1); tol 1. Slot occupants t vs
// t-2 differ by 8; scrub/poison rejected. hstate memset per launch (ABA).
// All spins bounded -> failures visible, no hangs.

#define BB 64
#define TT 256
#define HH 1024
#define LL 6
#define NG 8
#define GB 8
#define NQ 32
#define SJ 32
#define NTH 256
#define LH (LL * HH)      // 6144
#define MAXFIX (1 << 16)

#define HSTATE_BYTES (2ull * BB * LL * HH * 4)   // [parity][b][l][k], 3 MB

typedef float f32x4 __attribute__((ext_vector_type(4)));

static __device__ __forceinline__ float2 aload2(const float* p) {
    unsigned long long u = __hip_atomic_load((const unsigned long long*)p,
        __ATOMIC_RELAXED, __HIP_MEMORY_SCOPE_AGENT);
    union { unsigned long long u; float2 f; } c; c.u = u; return c.f;
}
static __device__ __forceinline__ void astore1(float* p, float v) {
    __hip_atomic_store(p, v, __ATOMIC_RELAXED, __HIP_MEMORY_SCOPE_AGENT);
}

__global__ void __launch_bounds__(NTH, 1)
rnn_kernel(const float* __restrict__ h0,
           const float* __restrict__ Whh,
           const float* __restrict__ bias_ih,
           const float* __restrict__ bias_bh,
           const float* __restrict__ w_out,
           const float* __restrict__ b_out,
           float* hstate,
           float* __restrict__ d_out)
{
    __shared__ f32x4 s4[GB * 256];          // 32 KB: s = prev + h_old
    __shared__ f32x4 hring[2][GB * 256];    // 64 KB: raw tagged H, cell-parity dbuf
    __shared__ float pred[2][4][SJ][10];    // 10 KB: k-reduce partials
    __shared__ float outred[2][4];

    const int tid = threadIdx.x;
    const int g   = blockIdx.x & 7;         // group (same XCD under round-robin)
    const int q   = blockIdx.x >> 3;        // j-slice 0..31
    const int gb  = g * GB;
    const int jl  = tid & 31;
    const int ks  = tid >> 5;               // k-slice 0..7
    const int wv  = tid >> 6;               // wave 0..3
    const int jg  = q * SJ + jl;

    // ---- W -> registers: 32 f32x4 = 128 VGPR (v8's proven budget)
    f32x4 wreg[32];
    {
        const f32x4* wrow = (const f32x4*)(Whh + (size_t)jg * HH) + ks * 32;
#pragma unroll
        for (int r = 0; r < 32; ++r) wreg[r] = wrow[r];
    }

    const float bias_j = bias_ih[jg] + bias_bh[jg];
    const f32x4 wo     = ((const f32x4*)w_out)[tid];
    const float bout   = b_out[0];

    // ---- hring[0] <- h0 layer 0 (raw, tagH = 0); same-thread slots
#pragma unroll
    for (int b = 0; b < GB; ++b)
        hring[0][b * 256 + tid] =
            *(const f32x4*)(h0 + ((size_t)0 * BB + gb + b) * HH + (tid << 2));
    float tagH = 0.f;

    for (int t = 0; t < TT; ++t) {
        const int   pw   = t & 1, pr = pw ^ 1;
        const float tagW = 8.0f + 8.0f * (float)((t >> 1) & 1);       // o(t)
        const float tagO = 8.0f + 8.0f * (float)(((t - 1) >> 1) & 1); // o(t-1)

        for (int l = 0; l < LL; ++l) {
            const int lp = l ? l - 1 : LL - 1;
            const int pp = l ? pw : pr;
            const int cp = l & 1;            // cell parity (LL even => alternates)

            // ---- P acquire (the critical chain)
            f32x4 P[GB]; float tagP;
            if (t == 0 && l == 0) {
                tagP = 0.f;                  // prev = h0 layer 5, plain loads
#pragma unroll
                for (int b = 0; b < GB; ++b)
                    P[b] = *(const f32x4*)(h0 + ((size_t)5 * BB + gb + b) * HH + (tid << 2));
            } else {
                tagP = l ? tagW : tagO;
                const float* baseP = hstate + (((size_t)pp * BB + gb) * LL + lp) * HH + (tid << 2);
#pragma unroll
                for (int b = 0; b < GB; ++b) {
                    const float* p = baseP + (size_t)b * LH;
                    float2 a = aload2(p), c = aload2(p + 2);
                    P[b] = (f32x4){a.x, a.y, c.x, c.y};
                }
                unsigned bad = 0;
#pragma unroll
                for (int b = 0; b < GB; ++b) {
                    if (fabsf(P[b].x - tagP) > 1.0f || fabsf(P[b].y - tagP) > 1.0f) bad |= 1u << (2 * b);
                    if (fabsf(P[b].z - tagP) > 1.0f || fabsf(P[b].w - tagP) > 1.0f) bad |= 2u << (2 * b);
                }
                for (int it = 0; bad && it < MAXFIX; ++it) {
                    if (it > 4) __builtin_amdgcn_s_sleep(1);   // hot window first
#pragma unroll
                    for (int b = 0; b < GB; ++b) {
                        const float* p = baseP + (size_t)b * LH;
                        if (bad & (1u << (2 * b))) {
                            float2 a = aload2(p);
                            if (fabsf(a.x - tagP) <= 1.0f && fabsf(a.y - tagP) <= 1.0f) {
                                P[b].x = a.x; P[b].y = a.y; bad &= ~(1u << (2 * b));
                            }
                        }
                        if (bad & (2u << (2 * b))) {
                            float2 c = aload2(p + 2);
                            if (fabsf(c.x - tagP) <= 1.0f && fabsf(c.y - tagP) <= 1.0f) {
                                P[b].z = c.x; P[b].w = c.y; bad &= ~(2u << (2 * b));
                            }
                        }
                    }
                }
            }

            // ---- stage s = (P - tagP) + (hring[cp] - tagH); both exact
#pragma unroll
            for (int b = 0; b < GB; ++b) {
                f32x4 h = hring[cp][b * 256 + tid];    // same-thread slot
                s4[b * 256 + tid] = (P[b] - tagP) + (h - tagH);
            }

            // ---- projection for (t-1): P at l==0 IS y(t-1, 5)
            if (l == 0 && t > 0 && q < GB) {
                f32x4 pd = P[q] - tagP;
                float val = pd.x * wo.x + pd.y * wo.y + pd.z * wo.z + pd.w * wo.w;
#pragma unroll
                for (int off = 32; off; off >>= 1) val += __shfl_down(val, off, 64);
                if ((tid & 63) == 0) outred[t & 1][wv] = val;
            }

            // ---- issue H prefetch for the NEXT cell (validated after FMA)
            const bool last = (t == TT - 1) && (l == LL - 1);
            const int  nl   = (l == LL - 1) ? 0 : l + 1;
            const int  ph   = (l == LL - 1) ? pw : pr;
            float tagHn = 0.f;
            bool  hn_g  = false;
            f32x4 Hn[GB];
            if (!last) {
                if (t == 0 && l < LL - 1) {            // next cell still t=0: plain h0
#pragma unroll
                    for (int b = 0; b < GB; ++b)
                        Hn[b] = *(const f32x4*)(h0 + ((size_t)nl * BB + gb + b) * HH + (tid << 2));
                } else {
                    hn_g  = true;
                    tagHn = (l == LL - 1) ? tagW : tagO;
                    const float* baseH = hstate + (((size_t)ph * BB + gb) * LL + nl) * HH + (tid << 2);
#pragma unroll
                    for (int b = 0; b < GB; ++b) {     // issue now; overlap FMA
                        const float* p = baseH + (size_t)b * LH;
                        float2 a = aload2(p), c = aload2(p + 2);
                        Hn[b] = (f32x4){a.x, a.y, c.x, c.y};
                    }
                }
            }

            __syncthreads();   // s4 + outred ready

            if (l == 0 && t > 0 && q < GB && tid == 0)
                d_out[(size_t)(gb + q) * TT + (t - 1)] =
                    outred[t & 1][0] + outred[t & 1][1] +
                    outred[t & 1][2] + outred[t & 1][3] + bout;

            // ---- 1024 reg-reg FMA, 8 independent accumulator chains
            float acc[GB];
#pragma unroll
            for (int b = 0; b < GB; ++b) acc[b] = 0.f;
            const f32x4* xb = s4 + ks * 32;
#pragma unroll
            for (int b = 0; b < GB; ++b) {
#pragma unroll
                for (int k4 = 0; k4 < 32; ++k4) {
                    f32x4 x = xb[b * 256 + k4];   // broadcast LDS read
                    f32x4 w = wreg[k4];           // register-resident W
                    acc[b] = fmaf(w.x, x.x, fmaf(w.y, x.y,
                             fmaf(w.z, x.z, fmaf(w.w, x.w, acc[b]))));
                }
            }

            // ---- finalize prefetch: validate Hn (rarely bad), commit to ring
            if (!last) {
                if (hn_g) {
                    const float* baseH = hstate + (((size_t)ph * BB + gb) * LL + nl) * HH + (tid << 2);
                    unsigned bad = 0;
#pragma unroll
                    for (int b = 0; b < GB; ++b) {
                        if (fabsf(Hn[b].x - tagHn) > 1.0f || fabsf(Hn[b].y - tagHn) > 1.0f) bad |= 1u << (2 * b);
                        if (fabsf(Hn[b].z - tagHn) > 1.0f || fabsf(Hn[b].w - tagHn) > 1.0f) bad |= 2u << (2 * b);
                    }
                    for (int it = 0; bad && it < MAXFIX; ++it) {
                        if (it > 2) __builtin_amdgcn_s_sleep(1);
#pragma unroll
                        for (int b = 0; b < GB; ++b) {
                            const float* p = baseH + (size_t)b * LH;
                            if (bad & (1u << (2 * b))) {
                                float2 a = aload2(p);
                                if (fabsf(a.x - tagHn) <= 1.0f && fabsf(a.y - tagHn) <= 1.0f) {
                                    Hn[b].x = a.x; Hn[b].y = a.y; bad &= ~(1u << (2 * b));
                                }
                            }
                            if (bad & (2u << (2 * b))) {
                                float2 c = aload2(p + 2);
                                if (fabsf(c.x - tagHn) <= 1.0f && fabsf(c.y - tagHn) <= 1.0f) {
                                    Hn[b].z = c.x; Hn[b].w = c.y; bad &= ~(2u << (2 * b));
                                }
                            }
                        }
                    }
                }
#pragma unroll
                for (int b = 0; b < GB; ++b)
                    hring[cp ^ 1][b * 256 + tid] = Hn[b];   // same-thread slot
                tagH = tagHn;
            }

            // ---- k-reduce: shfl merge ks pairs, then 4 waves via LDS (dbuf)
#pragma unroll
            for (int b = 0; b < GB; ++b) acc[b] += __shfl_xor(acc[b], 32);
            if ((tid & 63) < 32) {
#pragma unroll
                for (int b = 0; b < GB; ++b) pred[cp][wv][jl][b] = acc[b];
            }
            __syncthreads();

            const int bb = tid >> 5;     // thread (jl, bb) owns output
            float ysum = pred[cp][0][jl][bb] + pred[cp][1][jl][bb]
                       + pred[cp][2][jl][bb] + pred[cp][3][jl][bb];
            float y = tanhf(ysum + bias_j);
            astore1(&hstate[(((size_t)pw * BB + gb + bb) * LL + l) * HH + jg],
                    y + tagW);           // tagged publish: the store IS the flag

            if (t == TT - 1)
                d_out[(size_t)BB * TT + ((size_t)l * BB + gb + bb) * HH + jg] = y;
        }
    }

    // ---- epilogue: out[b, 255] from y(255, 5) (parity 1, tag o(255)=16)
    if (q < GB) {
        const float* P5 = hstate + (((size_t)1 * BB + gb + q) * LL + 5) * HH + (tid << 2);
        f32x4 a;
        for (int it = 0; it < MAXFIX; ++it) {
            float2 a0 = aload2(P5), a1 = aload2(P5 + 2);
            a = (f32x4){a0.x, a0.y, a1.x, a1.y};
            if (fabsf(a.x - 16.0f) <= 1.0f && fabsf(a.y - 16.0f) <= 1.0f &&
                fabsf(a.z - 16.0f) <= 1.0f && fabsf(a.w - 16.0f) <= 1.0f) break;
            __builtin_amdgcn_s_sleep(1);
        }
        float val = (a.x - 16.0f) * wo.x + (a.y - 16.0f) * wo.y
                  + (a.z - 16.0f) * wo.z + (a.w - 16.0f) * wo.w;
#pragma unroll
        for (int off = 32; off; off >>= 1) val += __shfl_down(val, off, 64);
        if ((tid & 63) == 0) outred[0][wv] = val;
        __syncthreads();
        if (tid == 0)
            d_out[(size_t)(gb + q) * TT + (TT - 1)] =
                outred[0][0] + outred[0][1] + outred[0][2] + outred[0][3] + bout;
    }
}

extern "C" void kernel_launch(void* const* d_in, const int* in_sizes, int n_in,
                              void* d_out, int out_size, void* d_ws, size_t ws_size,
                              hipStream_t stream) {
    // inputs: 0:x(unused) 1:h0 2:weight_ih(unused) 3:bias_ih 4:weight_hh 5:bias_bh 6:w_out 7:b_out
    const float* h0      = (const float*)d_in[1];
    const float* bias_ih = (const float*)d_in[3];
    const float* Whh     = (const float*)d_in[4];
    const float* bias_bh = (const float*)d_in[5];
    const float* w_out   = (const float*)d_in[6];
    const float* b_out   = (const float*)d_in[7];

    float* hstate = (float*)d_ws;

    // scrub tags every launch: stale same-parity tags from a previous replay
    // could alias under block skew (ABA) -- 3MB async memset is ~us-scale.
    hipMemsetAsync(hstate, 0, HSTATE_BYTES, stream);
    rnn_kernel<<<NG * NQ, NTH, 0, stream>>>(h0, Whh, bias_ih, bias_bh,
                                            w_out, b_out, hstate,
                                            (float*)d_out);
}

// Round 15
// 39176.300 us; speedup vs baseline: 6.9481x; 6.9481x over previous
//
#include <hip/hip_runtime.h>

// B=64, T=256, H=1024, L=6. Cell: h = tanh((prev + h_old) @ W^T + b1 + b2).
// v15 = v8 (PASSING 18.2ms) with the bulk data moved off the MALL onto the
// shared XCD L2. Coherence map from r8-r11: agent atomics = MALL (works,
// ~us); sc0 loads read MALL (r10 fail); agent stores bypass L2 (r11 fail).
// Untested combo used here: PLAIN stores (write-through L1 -> XCD L2) +
// PLAIN loads (L1 miss -> same L2). Detection via 1-word MALL sentinels
// (agent atomics, proven): producer posts monotonic phase counter after
// __syncthreads drains its y-stores into L2; consumers poll 32 sentinels
// then bulk-gather 64KB from L2. Data-as-flag tags kept as safety net:
// stale L1 lines (same addr last read 2 cells ago, tag differs by 8) are
// rejected and fixed by a wave-level 32KB scrub + reload. Sentinel gating
// bounds inter-block skew to 1 phase -> anti-deps safe. XCD co-location
// guard (r10) falls back to exact-v8 agent transport. Register budget = v8
// (wreg 128 + H/P 64; v14's extra in-flight gather spilled -> 272ms).

#define BB 64
#define TT 256
#define HH 1024
#define LL 6
#define NG 8
#define GB 8
#define NQ 32
#define SJ 32
#define NTH 256
#define LH (LL * HH)
#define MAXPOLL (1 << 20)
#define MAXFIX  (1 << 13)
#define FLAG_PAD 32

#define HSTATE_BYTES (2ull * BB * LL * HH * 4)            // 3 MB
#define FLAGS_OFF    HSTATE_BYTES
#define FLAGS_BYTES  ((size_t)NG * NQ * FLAG_PAD * 4)     // 32 KB
#define XCD_OFF      (FLAGS_OFF + FLAGS_BYTES)
#define WS_CLEAR     (XCD_OFF + 4096)

typedef float f32x4 __attribute__((ext_vector_type(4)));
template <bool F> struct BoolC { static constexpr bool value = F; };

static __device__ __forceinline__ float2 aload2(const float* p) {
    unsigned long long u = __hip_atomic_load((const unsigned long long*)p,
        __ATOMIC_RELAXED, __HIP_MEMORY_SCOPE_AGENT);
    union { unsigned long long u; float2 f; } c; c.u = u; return c.f;
}
static __device__ __forceinline__ void astoref(float* p, float v) {
    __hip_atomic_store(p, v, __ATOMIC_RELAXED, __HIP_MEMORY_SCOPE_AGENT);
}
static __device__ __forceinline__ unsigned aloadu(const unsigned* p) {
    return __hip_atomic_load(p, __ATOMIC_RELAXED, __HIP_MEMORY_SCOPE_AGENT);
}
static __device__ __forceinline__ void astoreu(unsigned* p, unsigned v) {
    __hip_atomic_store(p, v, __ATOMIC_RELAXED, __HIP_MEMORY_SCOPE_AGENT);
}

// 8 x 16B plain (L1/L2-cacheable) loads at base + r*LH
static __device__ __forceinline__ void pgather8(const float* base, f32x4* o) {
    asm volatile(
        "global_load_dwordx4 %0, %8, off\n\t"
        "global_load_dwordx4 %1, %9, off\n\t"
        "global_load_dwordx4 %2, %10, off\n\t"
        "global_load_dwordx4 %3, %11, off\n\t"
        "global_load_dwordx4 %4, %12, off\n\t"
        "global_load_dwordx4 %5, %13, off\n\t"
        "global_load_dwordx4 %6, %14, off\n\t"
        "global_load_dwordx4 %7, %15, off\n\t"
        "s_waitcnt vmcnt(0)"
        : "=&v"(o[0]), "=&v"(o[1]), "=&v"(o[2]), "=&v"(o[3]),
          "=&v"(o[4]), "=&v"(o[5]), "=&v"(o[6]), "=&v"(o[7])
        : "v"(base),        "v"(base + LH),     "v"(base + 2 * LH),
          "v"(base + 3 * LH), "v"(base + 4 * LH), "v"(base + 5 * LH),
          "v"(base + 6 * LH), "v"(base + 7 * LH)
        : "memory");
}
static __device__ __forceinline__ void agather8(const float* base, f32x4* o) {
#pragma unroll
    for (int r = 0; r < GB; ++r) {
        const float* p = base + (size_t)r * LH;
        float2 a = aload2(p), c = aload2(p + 2);
        o[r] = (f32x4){a.x, a.y, c.x, c.y};
    }
}
static __device__ __forceinline__ f32x4 pload16(const float* p) {
    f32x4 v;
    asm volatile("global_load_dwordx4 %0, %1, off\n\ts_waitcnt vmcnt(0)"
                 : "=&v"(v) : "v"(p) : "memory");
    return v;
}

// wave-level 32KB L1 scrub: 64 lanes x 512B of plain loads from a read-only
// window (Whh). Evicts stale hstate lines from this CU's L1.
static __device__ __forceinline__ void wave_scrub(const float* w, int lane) {
#pragma unroll
    for (int i = 0; i < 32; ++i) {
        f32x4 d;
        asm volatile("global_load_dwordx4 %0, %1, off"
                     : "=&v"(d) : "v"(w + lane * 128 + i * 4) : "memory");
        asm volatile("" :: "v"(d));
    }
    asm volatile("s_waitcnt vmcnt(0)" ::: "memory");
}

template <bool FAST>
static __device__ __forceinline__ void gather_val(const float* base, f32x4* V,
                                                  float tag, float tol,
                                                  const float* scrubsrc,
                                                  int lane, unsigned& scnt) {
    if constexpr (FAST) pgather8(base, V); else agather8(base, V);
    unsigned bad = 0;
#pragma unroll
    for (int b = 0; b < GB; ++b) {
        if (fabsf(V[b].x - tag) > tol || fabsf(V[b].y - tag) > tol) bad |= 1u << (2 * b);
        if (fabsf(V[b].z - tag) > tol || fabsf(V[b].w - tag) > tol) bad |= 2u << (2 * b);
    }
    for (int it = 0; it < MAXFIX; ++it) {
        if constexpr (FAST) { if (__ballot(bad != 0) == 0) break; }
        else                { if (!bad) break; }
        if constexpr (FAST) wave_scrub(scrubsrc + ((scnt++ & 1u) << 13), lane);
        else if (it > 4) __builtin_amdgcn_s_sleep(1);
#pragma unroll
        for (int b = 0; b < GB; ++b) {
            if (!(bad & (3u << (2 * b)))) continue;
            const float* p = base + (size_t)b * LH;
            f32x4 nv;
            if constexpr (FAST) nv = pload16(p);
            else { float2 a = aload2(p), c = aload2(p + 2); nv = (f32x4){a.x, a.y, c.x, c.y}; }
            if (fabsf(nv.x - tag) <= tol && fabsf(nv.y - tag) <= tol) {
                V[b].x = nv.x; V[b].y = nv.y; bad &= ~(1u << (2 * b));
            }
            if (fabsf(nv.z - tag) <= tol && fabsf(nv.w - tag) <= tol) {
                V[b].z = nv.z; V[b].w = nv.w; bad &= ~(2u << (2 * b));
            }
        }
    }
}

template <bool FAST>
static __device__ __forceinline__ void publish1(float* p, float v) {
    if constexpr (FAST) *(volatile float*)p = v;   // plain: lands in XCD L2
    else astoref(p, v);                            // agent: MALL (v8 path)
}

__global__ void __launch_bounds__(NTH, 1)
rnn_kernel(const float* __restrict__ h0,
           const float* __restrict__ Whh,
           const float* __restrict__ bias_ih,
           const float* __restrict__ bias_bh,
           const float* __restrict__ w_out,
           const float* __restrict__ b_out,
           float* hstate, unsigned* flags, unsigned* xcdbuf,
           float* __restrict__ d_out)
{
    __shared__ f32x4    s4[GB * 256];        // 32 KB
    __shared__ float    pred[2][4][SJ][10];  // 10 KB
    __shared__ float    outred[2][4];
    __shared__ unsigned shx[NTH];
    __shared__ int      okf;

    const int tid  = threadIdx.x;
    const int bid  = blockIdx.x;
    const int g    = bid & 7;
    const int q    = bid >> 3;
    const int gb   = g * GB;
    const int jl   = tid & 31;
    const int ks   = tid >> 5;
    const int wv   = tid >> 6;
    const int lane = tid & 63;
    const int jg   = q * SJ + jl;

    f32x4 wreg[32];
    {
        const f32x4* wrow = (const f32x4*)(Whh + (size_t)jg * HH) + ks * 32;
#pragma unroll
        for (int r = 0; r < 32; ++r) wreg[r] = wrow[r];
    }
    const float bias_j = bias_ih[jg] + bias_bh[jg];
    const f32x4 wo     = ((const f32x4*)w_out)[tid];
    const float bout   = b_out[0];

    // ---- XCD co-location guard (unanimous; r10 logic)
    unsigned xid;
    asm("s_getreg_b32 %0, hwreg(HW_REG_XCC_ID)" : "=s"(xid));
    if (tid == 0) astoreu(&xcdbuf[bid], xid + 1u);
    {
        unsigned v = 0;
        for (int it = 0; it < (1 << 22); ++it) {
            v = aloadu(&xcdbuf[tid]);
            if (v) break;
            __builtin_amdgcn_s_sleep(8);
        }
        shx[tid] = v;
        if (tid == 0) okf = 1;
        __syncthreads();
        if (shx[tid] == 0 || shx[tid] != shx[tid & 7]) okf = 0;
        __syncthreads();
    }
    const bool fast = (okf != 0);

    unsigned* myflag = flags + ((size_t)(g * NQ + q)) * FLAG_PAD;

    auto body = [&](auto FC) __attribute__((always_inline)) {
        constexpr bool FAST = decltype(FC)::value;
        unsigned scnt = 0;

        // ---- init publish: h0 + 64 into parity-1 (this block: k-columns)
        {
            int bb = tid >> 5, k = q * SJ + (tid & 31);
#pragma unroll
            for (int l = 0; l < LL; ++l)
                publish1<FAST>(&hstate[(((size_t)1 * BB + gb + bb) * LL + l) * HH + k],
                               h0[((size_t)l * BB + gb + bb) * HH + k] + 64.0f);
        }
        __syncthreads();                       // drains vm: stores in L2/MALL
        if (tid == 0) astoreu(myflag, 1u);     // phase 0 (init) complete

        for (int t = 0; t < TT; ++t) {
            const int   pw   = t & 1, pr = pw ^ 1;
            const float tagW = 8.0f + 8.0f * (float)((t >> 1) & 1);
            const float tagO = 8.0f + 8.0f * (float)(((t - 1) >> 1) & 1);
            const float tagH = (t == 0) ? 64.0f : tagO;
            const float tolH = (t == 0) ? 16.0f : 1.0f;

            for (int l = 0; l < LL; ++l) {
                const int   lp   = l ? (l - 1) : (LL - 1);
                const int   pp   = l ? pw : pr;
                const float tagP = l ? tagW : tagH;
                const float tolP = l ? 1.0f : tolH;
                const int   cp   = l & 1;
                const unsigned need = (unsigned)(t * LL + l + 1);  // cell index c

                // ---- sentinel gate: all 32 producers completed phase c-1
                if (lane < NQ) {
                    const unsigned* fl = flags + ((size_t)(g * NQ + lane)) * FLAG_PAD;
                    for (int it = 0; it < MAXPOLL; ++it) {
                        if (aloadu(fl) >= need) break;
                        if (it > 2) __builtin_amdgcn_s_sleep(1);
                    }
                }
                asm volatile("" ::: "memory");

                // ---- bulk gather from L2 (fast) / MALL (slow), tag-verified
                const float* baseH = hstate + (((size_t)pr * BB + gb) * LL + l ) * HH + (tid << 2);
                const float* baseP = hstate + (((size_t)pp * BB + gb) * LL + lp) * HH + (tid << 2);
                f32x4 H[GB], P[GB];
                gather_val<FAST>(baseH, H, tagH, tolH, Whh, lane, scnt);
                gather_val<FAST>(baseP, P, tagP, tolP, Whh, lane, scnt);

#pragma unroll
                for (int b = 0; b < GB; ++b)
                    s4[b * 256 + tid] = (P[b] - tagP) + (H[b] - tagH);

                if (l == 0 && t > 0 && q < GB) {
                    f32x4 pd = P[q] - tagP;
                    float val = pd.x * wo.x + pd.y * wo.y + pd.z * wo.z + pd.w * wo.w;
#pragma unroll
                    for (int off = 32; off; off >>= 1) val += __shfl_down(val, off, 64);
                    if ((tid & 63) == 0) outred[t & 1][wv] = val;
                }
                __syncthreads();

                if (l == 0 && t > 0 && q < GB && tid == 0)
                    d_out[(size_t)(gb + q) * TT + (t - 1)] =
                        outred[t & 1][0] + outred[t & 1][1] +
                        outred[t & 1][2] + outred[t & 1][3] + bout;

                float acc[GB];
#pragma unroll
                for (int b = 0; b < GB; ++b) acc[b] = 0.f;
                const f32x4* xb = s4 + ks * 32;
#pragma unroll
                for (int b = 0; b < GB; ++b) {
#pragma unroll
                    for (int k4 = 0; k4 < 32; ++k4) {
                        f32x4 x = xb[b * 256 + k4];
                        f32x4 w = wreg[k4];
                        acc[b] = fmaf(w.x, x.x, fmaf(w.y, x.y,
                                 fmaf(w.z, x.z, fmaf(w.w, x.w, acc[b]))));
                    }
                }

#pragma unroll
                for (int b = 0; b < GB; ++b) acc[b] += __shfl_xor(acc[b], 32);
                if ((tid & 63) < 32) {
#pragma unroll
                    for (int b = 0; b < GB; ++b) pred[cp][wv][jl][b] = acc[b];
                }
                __syncthreads();

                const int bb = tid >> 5;
                float ysum = pred[cp][0][jl][bb] + pred[cp][1][jl][bb]
                           + pred[cp][2][jl][bb] + pred[cp][3][jl][bb];
                float y = tanhf(ysum + bias_j);
                publish1<FAST>(&hstate[(((size_t)pw * BB + gb + bb) * LL + l) * HH + jg],
                               y + tagW);
                if (t == TT - 1)
                    d_out[(size_t)BB * TT + ((size_t)l * BB + gb + bb) * HH + jg] = y;

                __syncthreads();                      // drain y-stores into L2
                if (tid == 0) astoreu(myflag, need + 1u);   // phase c complete
            }
        }

        // ---- epilogue: out[b,255] from y(255,5) (parity 1, tag 16)
        if (q < GB) {
            if (lane < NQ) {
                const unsigned* fl = flags + ((size_t)(g * NQ + lane)) * FLAG_PAD;
                for (int it = 0; it < MAXPOLL; ++it) {
                    if (aloadu(fl) >= (unsigned)(TT * LL + 1)) break;
                    if (it > 2) __builtin_amdgcn_s_sleep(1);
                }
            }
            asm volatile("" ::: "memory");
            const float* P5 = hstate + (((size_t)1 * BB + gb + q) * LL + 5) * HH + (tid << 2);
            f32x4 a;
            if constexpr (FAST) a = pload16(P5);
            else { float2 a0 = aload2(P5), a1 = aload2(P5 + 2); a = (f32x4){a0.x, a0.y, a1.x, a1.y}; }
            for (int it = 0; it < MAXFIX; ++it) {
                bool bad = fabsf(a.x - 16.0f) > 1.0f || fabsf(a.y - 16.0f) > 1.0f ||
                           fabsf(a.z - 16.0f) > 1.0f || fabsf(a.w - 16.0f) > 1.0f;
                if constexpr (FAST) { if (__ballot(bad) == 0) break; }
                else                { if (!bad) break; }
                if constexpr (FAST) wave_scrub(Whh + ((scnt++ & 1u) << 13), lane);
                else __builtin_amdgcn_s_sleep(1);
                if (bad) {
                    if constexpr (FAST) a = pload16(P5);
                    else { float2 a0 = aload2(P5), a1 = aload2(P5 + 2); a = (f32x4){a0.x, a0.y, a1.x, a1.y}; }
                }
            }
            float val = (a.x - 16.0f) * wo.x + (a.y - 16.0f) * wo.y
                      + (a.z - 16.0f) * wo.z + (a.w - 16.0f) * wo.w;
#pragma unroll
            for (int off = 32; off; off >>= 1) val += __shfl_down(val, off, 64);
            if ((tid & 63) == 0) outred[0][wv] = val;
            __syncthreads();
            if (tid == 0)
                d_out[(size_t)(gb + q) * TT + (TT - 1)] =
                    outred[0][0] + outred[0][1] + outred[0][2] + outred[0][3] + bout;
        }
    };

    if (fast) body(BoolC<true>{});
    else      body(BoolC<false>{});
}

extern "C" void kernel_launch(void* const* d_in, const int* in_sizes, int n_in,
                              void* d_out, int out_size, void* d_ws, size_t ws_size,
                              hipStream_t stream) {
    // inputs: 0:x(unused) 1:h0 2:weight_ih(unused) 3:bias_ih 4:weight_hh 5:bias_bh 6:w_out 7:b_out
    const float* h0      = (const float*)d_in[1];
    const float* bias_ih = (const float*)d_in[3];
    const float* Whh     = (const float*)d_in[4];
    const float* bias_bh = (const float*)d_in[5];
    const float* w_out   = (const float*)d_in[6];
    const float* b_out   = (const float*)d_in[7];

    float*    hstate = (float*)d_ws;
    unsigned* flags  = (unsigned*)((char*)d_ws + FLAGS_OFF);
    unsigned* xcdbuf = (unsigned*)((char*)d_ws + XCD_OFF);

    // scrub state + sentinels + guard slots every launch (replay-safe; the
    // flag reset is CORRECTNESS-critical: stale counters would skip gating)
    hipMemsetAsync(d_ws, 0, WS_CLEAR, stream);
    rnn_kernel<<<NG * NQ, NTH, 0, stream>>>(h0, Whh, bias_ih, bias_bh,
                                            w_out, b_out, hstate, flags, xcdbuf,
                                            (float*)d_out);
}